// Round 23
// baseline (60.619 us; speedup 1.0000x reference)
//
#include <hip/hip_runtime.h>
#include <hip/hip_bf16.h>
#include <stdint.h>

// CA model: B=8, H=256, W=256, C=16, HID=128, steps=2 (fixed by setup_inputs).
// Round 23: round-22 structure (best, 57.7us) + fast bf16 packing in the hot
// path: pkbf(lo,hi) = 2x v_add 0x8000 (round-nearest, ties-away) + 1x
// v_perm_b32 -> one u32 of 2 bf16. Replaces ~4-5-op __float2bfloat16 per
// element + short inserts (~145 VALU/MTSTEP -> ~60). Fragment selects done
// word-level (4 cndmask vs 8). Prep keeps RNE. All else identical.

#define NB 8
#define NH 256
#define NW 256
#define NC 16
#define WOFF 65536   // tmp offset in d_ws when prep region in use (20KB used)

typedef __attribute__((ext_vector_type(8))) short short8;
typedef __attribute__((ext_vector_type(4))) float floatx4;
typedef __attribute__((ext_vector_type(4))) uint32_t uint32x4;

__host__ __device__ inline void tf2x32(uint32_t k0, uint32_t k1,
                                       uint32_t x0, uint32_t x1,
                                       uint32_t& o0, uint32_t& o1) {
  const uint32_t ks2 = k0 ^ k1 ^ 0x1BD11BDAu;
  x0 += k0; x1 += k1;
#define RL(v, d) (((v) << (d)) | ((v) >> (32 - (d))))
#define R4(a, b, c, d)                          \
  x0 += x1; x1 = RL(x1, a); x1 ^= x0;           \
  x0 += x1; x1 = RL(x1, b); x1 ^= x0;           \
  x0 += x1; x1 = RL(x1, c); x1 ^= x0;           \
  x0 += x1; x1 = RL(x1, d); x1 ^= x0;
  R4(13, 15, 26, 6);  x0 += k1;  x1 += ks2 + 1u;
  R4(17, 29, 16, 24); x0 += ks2; x1 += k0 + 2u;
  R4(13, 15, 26, 6);  x0 += k0;  x1 += k1 + 3u;
  R4(17, 29, 16, 24); x0 += k1;  x1 += ks2 + 4u;
  R4(13, 15, 26, 6);  x0 += ks2; x1 += k0 + 5u;
#undef R4
#undef RL
  o0 = x0; o1 = x1;
}

__device__ inline short bfr(float x) {
  __hip_bfloat16 h = __float2bfloat16(x);
  return *reinterpret_cast<short*>(&h);
}

// fast pack: 2 fp32 -> u32 of 2 bf16 (lo in low 16, hi in high 16).
// round-to-nearest (ties away): +0x8000 then take high halves via v_perm.
__device__ inline uint32_t pkbf(float lo, float hi) {
  const uint32_t bl = __float_as_uint(lo) + 0x8000u;
  const uint32_t bh = __float_as_uint(hi) + 0x8000u;
  return __builtin_amdgcn_perm(bh, bl, 0x07060302u);
}

// ---- parallel prep: 20 blocks x 64 lanes, one fragment per block ----
// W0 sobel columns pre-scaled by 1/8 (power-of-2, bit-identical products) so
// kernel tap weights are inline consts; K-pad bias at k=48 (A=b0[o], B=1).
__global__ __launch_bounds__(64) void ca_prep(
    const float* __restrict__ W0, const float* __restrict__ b0,
    const float* __restrict__ W1, short* __restrict__ wbuf) {
  const int lane = threadIdx.x;
  const int c15 = lane & 15;
  const int g = lane >> 4;
  const int fi = blockIdx.x;   // 0..19
  short8 f;
  if (fi < 16) {
    const int n = fi >> 1;
    const int o = 16 * n + c15;
    if ((fi & 1) == 0) {
      const float s0 = (g < 2) ? 1.0f : 0.125f;   // identity | c1(scaled)
      const float* p = W0 + o * 48 + 8 * g;
      const floatx4 v0 = *reinterpret_cast<const floatx4*>(p);
      const floatx4 v1 = *reinterpret_cast<const floatx4*>(p + 4);
      f[0] = bfr(v0.x * s0); f[1] = bfr(v0.y * s0);
      f[2] = bfr(v0.z * s0); f[3] = bfr(v0.w * s0);
      f[4] = bfr(v1.x * s0); f[5] = bfr(v1.y * s0);
      f[6] = bfr(v1.z * s0); f[7] = bfr(v1.w * s0);
    } else {
      if (g < 2) {   // c2 columns (scaled)
        const float* p1 = W0 + o * 48 + 32 + 8 * g;
        const floatx4 u0 = *reinterpret_cast<const floatx4*>(p1);
        const floatx4 u1 = *reinterpret_cast<const floatx4*>(p1 + 4);
        f[0] = bfr(u0.x * 0.125f); f[1] = bfr(u0.y * 0.125f);
        f[2] = bfr(u0.z * 0.125f); f[3] = bfr(u0.w * 0.125f);
        f[4] = bfr(u1.x * 0.125f); f[5] = bfr(u1.y * 0.125f);
        f[6] = bfr(u1.z * 0.125f); f[7] = bfr(u1.w * 0.125f);
      } else {
#pragma unroll
        for (int j = 0; j < 8; ++j) f[j] = 0;
        if (g == 2) f[0] = bfr(b0[o]);   // A[o][48] = b0[o] (K-pad bias)
      }
    }
  } else {
    const int s = fi - 16;   // tau(s,8g+j)=32s+16*(j>>2)+4g+(j&3)
    const float* p = W1 + c15 * 128;
#pragma unroll
    for (int j = 0; j < 8; ++j)
      f[j] = bfr(p[32 * s + 16 * (j >> 2) + 4 * g + (j & 3)]);
  }
  reinterpret_cast<short8*>(wbuf)[fi * 64 + lane] = f;
}

template <bool PRE>
__global__ __launch_bounds__(64, 2) void ca_step(
    const float* __restrict__ xin, float* __restrict__ xout,
    const float* __restrict__ W0, const float* __restrict__ b0,
    const float* __restrict__ W1, const short* __restrict__ wfrag,
    uint32_t fk0, uint32_t fk1) {
  // two fp32 x tiles + halo (6 rows x 18 cols), 16B-chunk XOR-swizzled
  __shared__ float xs[2][6 * 18 * 16];

  const int tid = threadIdx.x;
  const int bt = blockIdx.x;
  const int wt = bt & 15;
  const int ht16 = (bt >> 4) & 15;
  const int b = bt >> 8;
  const int h0 = ht16 * 16;
  const int w0 = wt * 16;

  const int lane = tid;
  const int c15 = lane & 15;
  const int g = lane >> 4;

  auto xsaddr = [&](float* base, int row, int col, int chunk) -> floatx4* {
    const int off = (row * 18 + col) * 64 + ((chunk ^ ((col >> 1) & 3)) << 4);
    return reinterpret_cast<floatx4*>(reinterpret_cast<char*>(base) + off);
  };

  // ---- weight fragments, loaded once per wave ----
  short8 w0f[8][2];
  short8 w1f[4];
  if constexpr (PRE) {
    const short8* wf = reinterpret_cast<const short8*>(wfrag);
#pragma unroll
    for (int n = 0; n < 8; ++n) {
      w0f[n][0] = wf[(2 * n) * 64 + lane];
      w0f[n][1] = wf[(2 * n + 1) * 64 + lane];
    }
#pragma unroll
    for (int s = 0; s < 4; ++s) w1f[s] = wf[(16 + s) * 64 + lane];
  } else {
    const float s0 = (g < 2) ? 1.0f : 0.125f;
#pragma unroll
    for (int n = 0; n < 8; ++n) {
      const int o = 16 * n + c15;
      const float* p = W0 + o * 48 + 8 * g;
      const floatx4 v0 = *reinterpret_cast<const floatx4*>(p);
      const floatx4 v1 = *reinterpret_cast<const floatx4*>(p + 4);
      short8 f;
      f[0] = bfr(v0.x * s0); f[1] = bfr(v0.y * s0);
      f[2] = bfr(v0.z * s0); f[3] = bfr(v0.w * s0);
      f[4] = bfr(v1.x * s0); f[5] = bfr(v1.y * s0);
      f[6] = bfr(v1.z * s0); f[7] = bfr(v1.w * s0);
      w0f[n][0] = f;
      short8 f1;
      if (g < 2) {
        const float* p1 = W0 + o * 48 + 32 + 8 * g;
        const floatx4 u0 = *reinterpret_cast<const floatx4*>(p1);
        const floatx4 u1 = *reinterpret_cast<const floatx4*>(p1 + 4);
        f1[0] = bfr(u0.x * 0.125f); f1[1] = bfr(u0.y * 0.125f);
        f1[2] = bfr(u0.z * 0.125f); f1[3] = bfr(u0.w * 0.125f);
        f1[4] = bfr(u1.x * 0.125f); f1[5] = bfr(u1.y * 0.125f);
        f1[6] = bfr(u1.z * 0.125f); f1[7] = bfr(u1.w * 0.125f);
      } else {
#pragma unroll
        for (int j = 0; j < 8; ++j) f1[j] = 0;
        if (g == 2) f1[0] = bfr(b0[o]);
      }
      w0f[n][1] = f1;
    }
#pragma unroll
    for (int s = 0; s < 4; ++s) {
      const float* p = W1 + c15 * 128;
      short8 f;
#pragma unroll
      for (int j = 0; j < 8; ++j)
        f[j] = bfr(p[32 * s + 16 * (j >> 2) + 4 * g + (j & 3)]);
      w1f[s] = f;
    }
  }

  const int cc = 2 * (g & 1);   // chunk pair base for this lane's 8 channels
  const bool lo = (g < 2);
  const int col = 1 + c15;

  // ---- staging helpers: 432 16B chunks per tile, 7 per lane ----
  auto load_ph = [&](int h0t, floatx4* stg) {
#pragma unroll
    for (int i = 0; i < 7; ++i) {
      const int f = lane + 64 * i;
      floatx4 v = {0.f, 0.f, 0.f, 0.f};
      if (f < 432) {
        const int row = f / 72;
        const int rem = f - row * 72;
        const int cl = rem >> 2;
        const int q = rem & 3;
        const int gh = h0t - 1 + row;
        const int gw = w0 - 1 + cl;
        if ((unsigned)gh < (unsigned)NH && (unsigned)gw < (unsigned)NW)
          v = *reinterpret_cast<const floatx4*>(
              xin + (((size_t)b * NH + gh) * NW + gw) * NC + 4 * q);
      }
      stg[i] = v;
    }
  };
  auto write_ph = [&](float* buf, const floatx4* stg) {
#pragma unroll
    for (int i = 0; i < 7; ++i) {
      const int f = lane + 64 * i;
      if (f < 432) {
        const int row = f / 72;
        const int rem = f - row * 72;
        const int cl = rem >> 2;
        const int q = rem & 3;
        *xsaddr(buf, row, cl, q) = stg[i];
      }
    }
  };

  // rolling-partial: lane's partial + center for row ROW
  //   lo (c2 feeder): Hd = v[col+1] - v[col-1]
  //   hi (c1 feeder): Hs = v[col-1] + 2*v[col] + v[col+1]
#define PART(DST, CEN, ROW)                                                  \
  {                                                                          \
    const floatx4 L0 = *xsaddr(xsb, (ROW), col - 1, cc);                     \
    const floatx4 L1 = *xsaddr(xsb, (ROW), col - 1, cc + 1);                 \
    const floatx4 C0 = *xsaddr(xsb, (ROW), col, cc);                         \
    const floatx4 C1 = *xsaddr(xsb, (ROW), col, cc + 1);                     \
    const floatx4 R0 = *xsaddr(xsb, (ROW), col + 1, cc);                     \
    const floatx4 R1 = *xsaddr(xsb, (ROW), col + 1, cc + 1);                 \
    DST[0] = lo ? (R0.x - L0.x) : (L0.x + 2.f * C0.x + R0.x);                \
    DST[1] = lo ? (R0.y - L0.y) : (L0.y + 2.f * C0.y + R0.y);                \
    DST[2] = lo ? (R0.z - L0.z) : (L0.z + 2.f * C0.z + R0.z);                \
    DST[3] = lo ? (R0.w - L0.w) : (L0.w + 2.f * C0.w + R0.w);                \
    DST[4] = lo ? (R1.x - L1.x) : (L1.x + 2.f * C1.x + R1.x);                \
    DST[5] = lo ? (R1.y - L1.y) : (L1.y + 2.f * C1.y + R1.y);                \
    DST[6] = lo ? (R1.z - L1.z) : (L1.z + 2.f * C1.z + R1.z);                \
    DST[7] = lo ? (R1.w - L1.w) : (L1.w + 2.f * C1.w + R1.w);                \
    CEN[0] = C0.x; CEN[1] = C0.y; CEN[2] = C0.z; CEN[3] = C0.w;              \
    CEN[4] = C1.x; CEN[5] = C1.y; CEN[6] = C1.z; CEN[7] = C1.w;              \
  }

  // one output row: combine partials, pack fragments (v_perm), MFMA, epilogue
#define MTSTEP(MTI, HP, HC, HN, CN)                                          \
  {                                                                          \
    const int r = 1 + (MTI);                                                 \
    float comb[8];                                                           \
    _Pragma("unroll")                                                        \
    for (int j = 0; j < 8; ++j)                                              \
      comb[j] = lo ? (HP[j] + 2.f * HC[j] + HN[j]) : (HN[j] - HP[j]);        \
    uint32x4 cw, nw, aw0, aw1;                                               \
    _Pragma("unroll")                                                        \
    for (int q = 0; q < 4; ++q) {                                            \
      cw[q] = pkbf(comb[2 * q], comb[2 * q + 1]);                            \
      nw[q] = pkbf(CN[2 * q], CN[2 * q + 1]);                                \
    }                                                                        \
    const uint32_t biasw = (g == 2) ? 0x3F80u : 0u;                          \
    aw0[0] = lo ? nw[0] : cw[0];                                             \
    aw0[1] = lo ? nw[1] : cw[1];                                             \
    aw0[2] = lo ? nw[2] : cw[2];                                             \
    aw0[3] = lo ? nw[3] : cw[3];                                             \
    aw1[0] = lo ? cw[0] : biasw;                                             \
    aw1[1] = lo ? cw[1] : 0u;                                                \
    aw1[2] = lo ? cw[2] : 0u;                                                \
    aw1[3] = lo ? cw[3] : 0u;                                                \
    const short8 a0 = *reinterpret_cast<short8*>(&aw0);                      \
    const short8 a1 = *reinterpret_cast<short8*>(&aw1);                      \
    floatx4 acc[8];                                                          \
    _Pragma("unroll")                                                        \
    for (int n = 0; n < 8; ++n) acc[n] = floatx4{0.f, 0.f, 0.f, 0.f};        \
    _Pragma("unroll")                                                        \
    for (int n = 0; n < 8; ++n)                                              \
      acc[n] = __builtin_amdgcn_mfma_f32_16x16x32_bf16(w0f[n][0], a0,        \
                                                       acc[n], 0, 0, 0);     \
    _Pragma("unroll")                                                        \
    for (int n = 0; n < 8; ++n)                                              \
      acc[n] = __builtin_amdgcn_mfma_f32_16x16x32_bf16(w0f[n][1], a1,        \
                                                       acc[n], 0, 0, 0);     \
    floatx4 acc2 = {0.f, 0.f, 0.f, 0.f};                                     \
    _Pragma("unroll")                                                        \
    for (int s = 0; s < 4; ++s) {                                            \
      uint32x4 bb;                                                           \
      bb[0] = pkbf(fmaxf(acc[2 * s][0], 0.f), fmaxf(acc[2 * s][1], 0.f));    \
      bb[1] = pkbf(fmaxf(acc[2 * s][2], 0.f), fmaxf(acc[2 * s][3], 0.f));    \
      bb[2] = pkbf(fmaxf(acc[2 * s + 1][0], 0.f),                            \
                   fmaxf(acc[2 * s + 1][1], 0.f));                           \
      bb[3] = pkbf(fmaxf(acc[2 * s + 1][2], 0.f),                            \
                   fmaxf(acc[2 * s + 1][3], 0.f));                           \
      const short8 b2 = *reinterpret_cast<short8*>(&bb);                     \
      acc2 = __builtin_amdgcn_mfma_f32_16x16x32_bf16(w1f[s], b2,             \
                                                     acc2, 0, 0, 0);         \
    }                                                                        \
    const floatx4 xv = *xsaddr(xsb, r, col, g);                              \
    const float mk = (float)((mball >> (16 * (MTI) + c15)) & 1ull);          \
    const float mk03 = (g == 0) ? 0.f : mk;                                  \
    floatx4 ov;                                                              \
    ov.x = xv.x + acc2.x * mk03;                                             \
    ov.y = xv.y + acc2.y * mk03;                                             \
    ov.z = xv.z + acc2.z * mk03;                                             \
    ov.w = xv.w + acc2.w * mk;                                               \
    const size_t cellg = ((size_t)(b * NH + h0t + (MTI))) * NW + w0 + c15;   \
    *reinterpret_cast<floatx4*>(xout + cellg * NC + 4 * g) = ov;             \
  }

  // tile 0 staged directly
  {
    floatx4 s0[7];
    load_ph(h0, s0);
    write_ph(reinterpret_cast<float*>(xs[0]), s0);
  }
  __syncthreads();

  int cur = 0;
#pragma unroll 1
  for (int t = 0; t < 4; ++t) {
    const int h0t = h0 + 4 * t;

    // async-STAGE: issue next tile's global loads BEFORE compute
    floatx4 stg[7];
    if (t < 3) {
      load_ph(h0t + 4, stg);
      asm volatile("" ::: "memory");   // pin loads above the compute phase
    }

    // fire mask: lane -> (row=lane>>4, col=lane&15), bit = 16*row+col
    uint64_t mball;
    {
      const int cellg = (b * NH + h0t + (lane >> 4)) * NW + w0 + c15;
      uint32_t r0, r1;
      tf2x32(fk0, fk1, 0u, (uint32_t)cellg, r0, r1);
      const uint32_t bits = r0 ^ r1;
      const float u = __uint_as_float((bits >> 9) | 0x3F800000u) - 1.0f;
      mball = __ballot(u > 0.5f);
    }

    float* xsb = reinterpret_cast<float*>(xs[cur]);

    float hpA[8], hpB[8], hpC[8], cnA[8], cnB[8], cnC[8];
    PART(hpA, cnA, 0)
    PART(hpB, cnB, 1)
    PART(hpC, cnC, 2)
    MTSTEP(0, hpA, hpB, hpC, cnB)
    PART(hpA, cnA, 3)
    MTSTEP(1, hpB, hpC, hpA, cnC)
    PART(hpB, cnB, 4)
    MTSTEP(2, hpC, hpA, hpB, cnA)
    PART(hpC, cnC, 5)
    MTSTEP(3, hpA, hpB, hpC, cnB)

    if (t < 3) {
      __syncthreads();   // WAR: reads of xs[cur^1] (tile t-1) fully drained
      write_ph(reinterpret_cast<float*>(xs[cur ^ 1]), stg);
      __syncthreads();   // staging visible before tile t+1 reads
      cur ^= 1;
    }
  }
#undef PART
#undef MTSTEP
}

extern "C" void kernel_launch(void* const* d_in, const int* in_sizes, int n_in,
                              void* d_out, int out_size, void* d_ws, size_t ws_size,
                              hipStream_t stream) {
  const float* x  = (const float*)d_in[0];
  const float* W0 = (const float*)d_in[1];
  const float* b0 = (const float*)d_in[2];
  const float* W1 = (const float*)d_in[3];
  float* out = (float*)d_out;

  const size_t tmp_bytes = (size_t)NB * NH * NW * NC * 4;   // 32 MiB
  const bool pre = ws_size >= (size_t)WOFF + tmp_bytes;
  short* wbuf = (short*)d_ws;
  float* tmp = pre ? (float*)((char*)d_ws + WOFF) : (float*)d_ws;

  uint32_t fa0, fa1, fb0, fb1;
  tf2x32(0u, 42u, 0u, 0u, fa0, fa1);  // fold_in(key(42), 0)
  tf2x32(0u, 42u, 0u, 1u, fb0, fb1);  // fold_in(key(42), 1)

  dim3 grid(NB * (NH / 16) * (NW / 16)), block(64);
  if (pre) {
    ca_prep<<<20, 64, 0, stream>>>(W0, b0, W1, wbuf);
    ca_step<true><<<grid, block, 0, stream>>>(x, tmp, W0, b0, W1, wbuf, fa0, fa1);
    ca_step<true><<<grid, block, 0, stream>>>(tmp, out, W0, b0, W1, wbuf, fb0, fb1);
  } else {
    ca_step<false><<<grid, block, 0, stream>>>(x, tmp, W0, b0, W1, nullptr, fa0, fa1);
    ca_step<false><<<grid, block, 0, stream>>>(tmp, out, W0, b0, W1, nullptr, fb0, fb1);
  }
}

// Round 24
// 57.561 us; speedup vs baseline: 1.0531x; 1.0531x over previous
//
#include <hip/hip_runtime.h>
#include <hip/hip_bf16.h>
#include <stdint.h>

// CA model: B=8, H=256, W=256, C=16, HID=128, steps=2 (fixed by setup_inputs).
// FINAL (round 24 = round 22, best measured 57.7us, reproduced twice).
// Structure: per step, 2048 blocks x 1 wave; each wave owns a 16x16 cell
// tile as 4 vertical 4-row sub-tiles with double-buffered LDS and an
// async-STAGE split (next tile's global loads issued before compute).
// Sobel is separable: each lane keeps a 3-row rolling window of its one
// needed horizontal partial (+ center), so each output row costs 6 LDS
// b128 reads + ~40 VALU + 20 MFMA. MLP on bf16 MFMA 16x16x32: GEMM1 uses
// prep-composed fragments (sobel columns pre-scaled 1/8 -> inline-const tap
// weights; bias folded into the K=48 pad slot), GEMM2 uses a tau-permuted
// W1 so its B-fragment is the lane's own relu'd accumulators (no cross-lane
// movement). Fire mask = JAX threefry2x32 partitionable bits via ballot.
// Weights prepped once into d_ws by a 20-block kernel. Residual path fp32.

#define NB 8
#define NH 256
#define NW 256
#define NC 16
#define WOFF 65536   // tmp offset in d_ws when prep region in use (20KB used)

typedef __attribute__((ext_vector_type(8))) short short8;
typedef __attribute__((ext_vector_type(4))) float floatx4;

__host__ __device__ inline void tf2x32(uint32_t k0, uint32_t k1,
                                       uint32_t x0, uint32_t x1,
                                       uint32_t& o0, uint32_t& o1) {
  const uint32_t ks2 = k0 ^ k1 ^ 0x1BD11BDAu;
  x0 += k0; x1 += k1;
#define RL(v, d) (((v) << (d)) | ((v) >> (32 - (d))))
#define R4(a, b, c, d)                          \
  x0 += x1; x1 = RL(x1, a); x1 ^= x0;           \
  x0 += x1; x1 = RL(x1, b); x1 ^= x0;           \
  x0 += x1; x1 = RL(x1, c); x1 ^= x0;           \
  x0 += x1; x1 = RL(x1, d); x1 ^= x0;
  R4(13, 15, 26, 6);  x0 += k1;  x1 += ks2 + 1u;
  R4(17, 29, 16, 24); x0 += ks2; x1 += k0 + 2u;
  R4(13, 15, 26, 6);  x0 += k0;  x1 += k1 + 3u;
  R4(17, 29, 16, 24); x0 += k1;  x1 += ks2 + 4u;
  R4(13, 15, 26, 6);  x0 += ks2; x1 += k0 + 5u;
#undef R4
#undef RL
  o0 = x0; o1 = x1;
}

__device__ inline short bfr(float x) {
  __hip_bfloat16 h = __float2bfloat16(x);
  return *reinterpret_cast<short*>(&h);
}

// ---- parallel prep: 20 blocks x 64 lanes, one fragment per block ----
// W0 sobel columns pre-scaled by 1/8 (power-of-2, bit-identical products) so
// kernel tap weights are inline consts; K-pad bias at k=48 (A=b0[o], B=1).
__global__ __launch_bounds__(64) void ca_prep(
    const float* __restrict__ W0, const float* __restrict__ b0,
    const float* __restrict__ W1, short* __restrict__ wbuf) {
  const int lane = threadIdx.x;
  const int c15 = lane & 15;
  const int g = lane >> 4;
  const int fi = blockIdx.x;   // 0..19
  short8 f;
  if (fi < 16) {
    const int n = fi >> 1;
    const int o = 16 * n + c15;
    if ((fi & 1) == 0) {
      const float s0 = (g < 2) ? 1.0f : 0.125f;   // identity | c1(scaled)
      const float* p = W0 + o * 48 + 8 * g;
      const floatx4 v0 = *reinterpret_cast<const floatx4*>(p);
      const floatx4 v1 = *reinterpret_cast<const floatx4*>(p + 4);
      f[0] = bfr(v0.x * s0); f[1] = bfr(v0.y * s0);
      f[2] = bfr(v0.z * s0); f[3] = bfr(v0.w * s0);
      f[4] = bfr(v1.x * s0); f[5] = bfr(v1.y * s0);
      f[6] = bfr(v1.z * s0); f[7] = bfr(v1.w * s0);
    } else {
      if (g < 2) {   // c2 columns (scaled)
        const float* p1 = W0 + o * 48 + 32 + 8 * g;
        const floatx4 u0 = *reinterpret_cast<const floatx4*>(p1);
        const floatx4 u1 = *reinterpret_cast<const floatx4*>(p1 + 4);
        f[0] = bfr(u0.x * 0.125f); f[1] = bfr(u0.y * 0.125f);
        f[2] = bfr(u0.z * 0.125f); f[3] = bfr(u0.w * 0.125f);
        f[4] = bfr(u1.x * 0.125f); f[5] = bfr(u1.y * 0.125f);
        f[6] = bfr(u1.z * 0.125f); f[7] = bfr(u1.w * 0.125f);
      } else {
#pragma unroll
        for (int j = 0; j < 8; ++j) f[j] = 0;
        if (g == 2) f[0] = bfr(b0[o]);   // A[o][48] = b0[o] (K-pad bias)
      }
    }
  } else {
    const int s = fi - 16;   // tau(s,8g+j)=32s+16*(j>>2)+4g+(j&3)
    const float* p = W1 + c15 * 128;
#pragma unroll
    for (int j = 0; j < 8; ++j)
      f[j] = bfr(p[32 * s + 16 * (j >> 2) + 4 * g + (j & 3)]);
  }
  reinterpret_cast<short8*>(wbuf)[fi * 64 + lane] = f;
}

template <bool PRE>
__global__ __launch_bounds__(64, 2) void ca_step(
    const float* __restrict__ xin, float* __restrict__ xout,
    const float* __restrict__ W0, const float* __restrict__ b0,
    const float* __restrict__ W1, const short* __restrict__ wfrag,
    uint32_t fk0, uint32_t fk1) {
  // two fp32 x tiles + halo (6 rows x 18 cols), 16B-chunk XOR-swizzled
  __shared__ float xs[2][6 * 18 * 16];

  const int tid = threadIdx.x;
  const int bt = blockIdx.x;
  const int wt = bt & 15;
  const int ht16 = (bt >> 4) & 15;
  const int b = bt >> 8;
  const int h0 = ht16 * 16;
  const int w0 = wt * 16;

  const int lane = tid;
  const int c15 = lane & 15;
  const int g = lane >> 4;

  auto xsaddr = [&](float* base, int row, int col, int chunk) -> floatx4* {
    const int off = (row * 18 + col) * 64 + ((chunk ^ ((col >> 1) & 3)) << 4);
    return reinterpret_cast<floatx4*>(reinterpret_cast<char*>(base) + off);
  };

  // ---- weight fragments, loaded once per wave ----
  short8 w0f[8][2];
  short8 w1f[4];
  if constexpr (PRE) {
    const short8* wf = reinterpret_cast<const short8*>(wfrag);
#pragma unroll
    for (int n = 0; n < 8; ++n) {
      w0f[n][0] = wf[(2 * n) * 64 + lane];
      w0f[n][1] = wf[(2 * n + 1) * 64 + lane];
    }
#pragma unroll
    for (int s = 0; s < 4; ++s) w1f[s] = wf[(16 + s) * 64 + lane];
  } else {
    const float s0 = (g < 2) ? 1.0f : 0.125f;
#pragma unroll
    for (int n = 0; n < 8; ++n) {
      const int o = 16 * n + c15;
      const float* p = W0 + o * 48 + 8 * g;
      const floatx4 v0 = *reinterpret_cast<const floatx4*>(p);
      const floatx4 v1 = *reinterpret_cast<const floatx4*>(p + 4);
      short8 f;
      f[0] = bfr(v0.x * s0); f[1] = bfr(v0.y * s0);
      f[2] = bfr(v0.z * s0); f[3] = bfr(v0.w * s0);
      f[4] = bfr(v1.x * s0); f[5] = bfr(v1.y * s0);
      f[6] = bfr(v1.z * s0); f[7] = bfr(v1.w * s0);
      w0f[n][0] = f;
      short8 f1;
      if (g < 2) {
        const float* p1 = W0 + o * 48 + 32 + 8 * g;
        const floatx4 u0 = *reinterpret_cast<const floatx4*>(p1);
        const floatx4 u1 = *reinterpret_cast<const floatx4*>(p1 + 4);
        f1[0] = bfr(u0.x * 0.125f); f1[1] = bfr(u0.y * 0.125f);
        f1[2] = bfr(u0.z * 0.125f); f1[3] = bfr(u0.w * 0.125f);
        f1[4] = bfr(u1.x * 0.125f); f1[5] = bfr(u1.y * 0.125f);
        f1[6] = bfr(u1.z * 0.125f); f1[7] = bfr(u1.w * 0.125f);
      } else {
#pragma unroll
        for (int j = 0; j < 8; ++j) f1[j] = 0;
        if (g == 2) f1[0] = bfr(b0[o]);
      }
      w0f[n][1] = f1;
    }
#pragma unroll
    for (int s = 0; s < 4; ++s) {
      const float* p = W1 + c15 * 128;
      short8 f;
#pragma unroll
      for (int j = 0; j < 8; ++j)
        f[j] = bfr(p[32 * s + 16 * (j >> 2) + 4 * g + (j & 3)]);
      w1f[s] = f;
    }
  }

  const int cc = 2 * (g & 1);   // chunk pair base for this lane's 8 channels
  const bool lo = (g < 2);
  const int col = 1 + c15;

  // ---- staging helpers: 432 16B chunks per tile, 7 per lane ----
  auto load_ph = [&](int h0t, floatx4* stg) {
#pragma unroll
    for (int i = 0; i < 7; ++i) {
      const int f = lane + 64 * i;
      floatx4 v = {0.f, 0.f, 0.f, 0.f};
      if (f < 432) {
        const int row = f / 72;
        const int rem = f - row * 72;
        const int cl = rem >> 2;
        const int q = rem & 3;
        const int gh = h0t - 1 + row;
        const int gw = w0 - 1 + cl;
        if ((unsigned)gh < (unsigned)NH && (unsigned)gw < (unsigned)NW)
          v = *reinterpret_cast<const floatx4*>(
              xin + (((size_t)b * NH + gh) * NW + gw) * NC + 4 * q);
      }
      stg[i] = v;
    }
  };
  auto write_ph = [&](float* buf, const floatx4* stg) {
#pragma unroll
    for (int i = 0; i < 7; ++i) {
      const int f = lane + 64 * i;
      if (f < 432) {
        const int row = f / 72;
        const int rem = f - row * 72;
        const int cl = rem >> 2;
        const int q = rem & 3;
        *xsaddr(buf, row, cl, q) = stg[i];
      }
    }
  };

  // rolling-partial: lane's partial + center for row ROW
  //   lo (c2 feeder): Hd = v[col+1] - v[col-1]
  //   hi (c1 feeder): Hs = v[col-1] + 2*v[col] + v[col+1]
#define PART(DST, CEN, ROW)                                                  \
  {                                                                          \
    const floatx4 L0 = *xsaddr(xsb, (ROW), col - 1, cc);                     \
    const floatx4 L1 = *xsaddr(xsb, (ROW), col - 1, cc + 1);                 \
    const floatx4 C0 = *xsaddr(xsb, (ROW), col, cc);                         \
    const floatx4 C1 = *xsaddr(xsb, (ROW), col, cc + 1);                     \
    const floatx4 R0 = *xsaddr(xsb, (ROW), col + 1, cc);                     \
    const floatx4 R1 = *xsaddr(xsb, (ROW), col + 1, cc + 1);                 \
    DST[0] = lo ? (R0.x - L0.x) : (L0.x + 2.f * C0.x + R0.x);                \
    DST[1] = lo ? (R0.y - L0.y) : (L0.y + 2.f * C0.y + R0.y);                \
    DST[2] = lo ? (R0.z - L0.z) : (L0.z + 2.f * C0.z + R0.z);                \
    DST[3] = lo ? (R0.w - L0.w) : (L0.w + 2.f * C0.w + R0.w);                \
    DST[4] = lo ? (R1.x - L1.x) : (L1.x + 2.f * C1.x + R1.x);                \
    DST[5] = lo ? (R1.y - L1.y) : (L1.y + 2.f * C1.y + R1.y);                \
    DST[6] = lo ? (R1.z - L1.z) : (L1.z + 2.f * C1.z + R1.z);                \
    DST[7] = lo ? (R1.w - L1.w) : (L1.w + 2.f * C1.w + R1.w);                \
    CEN[0] = C0.x; CEN[1] = C0.y; CEN[2] = C0.z; CEN[3] = C0.w;              \
    CEN[4] = C1.x; CEN[5] = C1.y; CEN[6] = C1.z; CEN[7] = C1.w;              \
  }

  // one output row: combine partials, build fragments, MFMA, epilogue
#define MTSTEP(MTI, HP, HC, HN, CN)                                          \
  {                                                                          \
    const int r = 1 + (MTI);                                                 \
    short8 a0, a1;                                                           \
    _Pragma("unroll")                                                        \
    for (int j = 0; j < 8; ++j) {                                            \
      const float comb =                                                     \
          lo ? (HP[j] + 2.f * HC[j] + HN[j]) : (HN[j] - HP[j]);              \
      const short sb = bfr(comb);                                            \
      a0[j] = lo ? bfr(CN[j]) : sb;                                          \
      a1[j] = lo ? sb : (short)0;                                            \
    }                                                                        \
    if (g == 2) a1[0] = bfr(1.0f);                                           \
    floatx4 acc[8];                                                          \
    _Pragma("unroll")                                                        \
    for (int n = 0; n < 8; ++n) acc[n] = floatx4{0.f, 0.f, 0.f, 0.f};        \
    _Pragma("unroll")                                                        \
    for (int n = 0; n < 8; ++n)                                              \
      acc[n] = __builtin_amdgcn_mfma_f32_16x16x32_bf16(w0f[n][0], a0,        \
                                                       acc[n], 0, 0, 0);     \
    _Pragma("unroll")                                                        \
    for (int n = 0; n < 8; ++n)                                              \
      acc[n] = __builtin_amdgcn_mfma_f32_16x16x32_bf16(w0f[n][1], a1,        \
                                                       acc[n], 0, 0, 0);     \
    floatx4 acc2 = {0.f, 0.f, 0.f, 0.f};                                     \
    _Pragma("unroll")                                                        \
    for (int s = 0; s < 4; ++s) {                                            \
      short8 b2;                                                             \
      _Pragma("unroll")                                                      \
      for (int j = 0; j < 8; ++j)                                            \
        b2[j] = bfr(fmaxf(acc[2 * s + (j >> 2)][j & 3], 0.f));               \
      acc2 = __builtin_amdgcn_mfma_f32_16x16x32_bf16(w1f[s], b2,             \
                                                     acc2, 0, 0, 0);         \
    }                                                                        \
    const floatx4 xv = *xsaddr(xsb, r, col, g);                              \
    const float mk = (float)((mball >> (16 * (MTI) + c15)) & 1ull);          \
    const float mk03 = (g == 0) ? 0.f : mk;                                  \
    floatx4 ov;                                                              \
    ov.x = xv.x + acc2.x * mk03;                                             \
    ov.y = xv.y + acc2.y * mk03;                                             \
    ov.z = xv.z + acc2.z * mk03;                                             \
    ov.w = xv.w + acc2.w * mk;                                               \
    const size_t cellg = ((size_t)(b * NH + h0t + (MTI))) * NW + w0 + c15;   \
    *reinterpret_cast<floatx4*>(xout + cellg * NC + 4 * g) = ov;             \
  }

  // tile 0 staged directly
  {
    floatx4 s0[7];
    load_ph(h0, s0);
    write_ph(reinterpret_cast<float*>(xs[0]), s0);
  }
  __syncthreads();

  int cur = 0;
#pragma unroll 1
  for (int t = 0; t < 4; ++t) {
    const int h0t = h0 + 4 * t;

    // async-STAGE: issue next tile's global loads BEFORE compute
    floatx4 stg[7];
    if (t < 3) {
      load_ph(h0t + 4, stg);
      asm volatile("" ::: "memory");   // pin loads above the compute phase
    }

    // fire mask: lane -> (row=lane>>4, col=lane&15), bit = 16*row+col
    uint64_t mball;
    {
      const int cellg = (b * NH + h0t + (lane >> 4)) * NW + w0 + c15;
      uint32_t r0, r1;
      tf2x32(fk0, fk1, 0u, (uint32_t)cellg, r0, r1);
      const uint32_t bits = r0 ^ r1;
      const float u = __uint_as_float((bits >> 9) | 0x3F800000u) - 1.0f;
      mball = __ballot(u > 0.5f);
    }

    float* xsb = reinterpret_cast<float*>(xs[cur]);

    float hpA[8], hpB[8], hpC[8], cnA[8], cnB[8], cnC[8];
    PART(hpA, cnA, 0)
    PART(hpB, cnB, 1)
    PART(hpC, cnC, 2)
    MTSTEP(0, hpA, hpB, hpC, cnB)
    PART(hpA, cnA, 3)
    MTSTEP(1, hpB, hpC, hpA, cnC)
    PART(hpB, cnB, 4)
    MTSTEP(2, hpC, hpA, hpB, cnA)
    PART(hpC, cnC, 5)
    MTSTEP(3, hpA, hpB, hpC, cnB)

    if (t < 3) {
      __syncthreads();   // WAR: reads of xs[cur^1] (tile t-1) fully drained
      write_ph(reinterpret_cast<float*>(xs[cur ^ 1]), stg);
      __syncthreads();   // staging visible before tile t+1 reads
      cur ^= 1;
    }
  }
#undef PART
#undef MTSTEP
}

extern "C" void kernel_launch(void* const* d_in, const int* in_sizes, int n_in,
                              void* d_out, int out_size, void* d_ws, size_t ws_size,
                              hipStream_t stream) {
  const float* x  = (const float*)d_in[0];
  const float* W0 = (const float*)d_in[1];
  const float* b0 = (const float*)d_in[2];
  const float* W1 = (const float*)d_in[3];
  float* out = (float*)d_out;

  const size_t tmp_bytes = (size_t)NB * NH * NW * NC * 4;   // 32 MiB
  const bool pre = ws_size >= (size_t)WOFF + tmp_bytes;
  short* wbuf = (short*)d_ws;
  float* tmp = pre ? (float*)((char*)d_ws + WOFF) : (float*)d_ws;

  uint32_t fa0, fa1, fb0, fb1;
  tf2x32(0u, 42u, 0u, 0u, fa0, fa1);  // fold_in(key(42), 0)
  tf2x32(0u, 42u, 0u, 1u, fb0, fb1);  // fold_in(key(42), 1)

  dim3 grid(NB * (NH / 16) * (NW / 16)), block(64);
  if (pre) {
    ca_prep<<<20, 64, 0, stream>>>(W0, b0, W1, wbuf);
    ca_step<true><<<grid, block, 0, stream>>>(x, tmp, W0, b0, W1, wbuf, fa0, fa1);
    ca_step<true><<<grid, block, 0, stream>>>(tmp, out, W0, b0, W1, wbuf, fb0, fb1);
  } else {
    ca_step<false><<<grid, block, 0, stream>>>(x, tmp, W0, b0, W1, nullptr, fa0, fa1);
    ca_step<false><<<grid, block, 0, stream>>>(tmp, out, W0, b0, W1, nullptr, fb0, fb1);
  }
}